// Round 1
// baseline (410.054 us; speedup 1.0000x reference)
//
#include <hip/hip_runtime.h>
#include <hip/hip_bf16.h>
#include <math.h>

// Problem constants
#define S_LEN 2048
#define D_MODEL 1024
#define NH 16
#define DKH 64
#define BSZ 2

typedef __attribute__((ext_vector_type(8))) short s16x8;
typedef __attribute__((ext_vector_type(4))) float f32x4;

__device__ __forceinline__ unsigned short f2bf(float f) {
  unsigned int u = __float_as_uint(f);
  return (unsigned short)((u + 0x7fffu + ((u >> 16) & 1u)) >> 16);
}

// ---------------- prep: rope table ----------------
__global__ void k_rope_table(float* __restrict__ cosT, float* __restrict__ sinT) {
  int idx = blockIdx.x * 256 + threadIdx.x;  // 2048*32
  if (idx >= S_LEN * 32) return;
  int s = idx >> 5, i = idx & 31;
  float theta = powf(10000.0f, -(float)i / 32.0f);
  float ang = (float)s * theta;
  float sv, cv;
  sincosf(ang, &sv, &cv);
  cosT[idx] = cv;
  sinT[idx] = sv;
}

// ---------------- prep: weight transpose f32[1024][1024] -> bf16 WT[n][k] ----------------
__global__ __launch_bounds__(256) void k_wtrans(const float* __restrict__ W,
                                                unsigned short* __restrict__ WT) {
  __shared__ float t[32][33];
  int n0 = blockIdx.x * 32, k0 = blockIdx.y * 32;
  int tx = threadIdx.x & 31, ty = threadIdx.x >> 5;  // ty 0..7
#pragma unroll
  for (int p = 0; p < 4; ++p)
    t[ty + p * 8][tx] = W[(size_t)(k0 + ty + p * 8) * 1024 + n0 + tx];
  __syncthreads();
#pragma unroll
  for (int p = 0; p < 4; ++p)
    WT[(size_t)(n0 + ty + p * 8) * 1024 + k0 + tx] = f2bf(t[tx][ty + p * 8]);
}

// ---------------- prep: v transpose  vl[bh][s][d] -> vt[bh][d][s] (bf16) ----------------
__global__ __launch_bounds__(256) void k_vtrans(const unsigned short* __restrict__ vl,
                                                unsigned short* __restrict__ vt) {
  __shared__ unsigned short t[64][65];
  int bh = blockIdx.y;
  int s0 = blockIdx.x * 64;
  int tx = threadIdx.x & 3;   // 4 chunks of 16
  int r = threadIdx.x >> 2;   // 64 rows
  const unsigned short* src = vl + (size_t)bh * S_LEN * DKH + (size_t)s0 * DKH;
  s16x8 a = *(const s16x8*)(src + r * 64 + tx * 16);
  s16x8 b = *(const s16x8*)(src + r * 64 + tx * 16 + 8);
#pragma unroll
  for (int j = 0; j < 8; ++j) { t[r][tx * 16 + j] = (unsigned short)a[j]; t[r][tx * 16 + 8 + j] = (unsigned short)b[j]; }
  __syncthreads();
  unsigned short* dst = vt + (size_t)bh * DKH * S_LEN + (size_t)r * S_LEN + s0;
  s16x8 o0, o1;
#pragma unroll
  for (int j = 0; j < 8; ++j) { o0[j] = (short)t[tx * 16 + j][r]; o1[j] = (short)t[tx * 16 + 8 + j][r]; }
  *(s16x8*)(dst + tx * 16) = o0;
  *(s16x8*)(dst + tx * 16 + 8) = o1;
}

// ---------------- QKV projection GEMM + bias + RoPE ----------------
// Q f32 [4096][1024] @ WTqkv bf16 [3072][1024] (n-major) -> ql/kl bf16 [bh][s][d], vl bf16
__global__ __launch_bounds__(256) void k_qkv(
    const float* __restrict__ Q, const unsigned short* __restrict__ WTqkv,
    const float* __restrict__ bq, const float* __restrict__ bk, const float* __restrict__ bv,
    const float* __restrict__ cosT, const float* __restrict__ sinT,
    unsigned short* __restrict__ ql, unsigned short* __restrict__ kl,
    unsigned short* __restrict__ vl) {
  __shared__ unsigned short As[128][72];
  __shared__ unsigned short Bs[128][72];
  const int m0 = blockIdx.y * 128;
  const int n0 = blockIdx.x * 128;
  const int tid = threadIdx.x;
  const int lane = tid & 63, wave = tid >> 6;
  const int wm = (wave >> 1) * 64, wn = (wave & 1) * 64;
  const int lr = lane & 15, lg = lane >> 4;
  const int widx = n0 >> 10;  // 0=q 1=k 2=v
  const float* bias = widx == 0 ? bq : (widx == 1 ? bk : bv);

  f32x4 acc[4][4] = {};
  const int arow = tid >> 1, ahalf = tid & 1;

  for (int k0 = 0; k0 < 1024; k0 += 64) {
    __syncthreads();
    {
      const float* src = Q + (size_t)(m0 + arow) * 1024 + k0 + ahalf * 32;
      unsigned short* dstp = &As[arow][ahalf * 32];
#pragma unroll
      for (int j = 0; j < 4; ++j) {
        float4 v0 = ((const float4*)src)[2 * j];
        float4 v1 = ((const float4*)src)[2 * j + 1];
        s16x8 o;
        o[0] = (short)f2bf(v0.x); o[1] = (short)f2bf(v0.y); o[2] = (short)f2bf(v0.z); o[3] = (short)f2bf(v0.w);
        o[4] = (short)f2bf(v1.x); o[5] = (short)f2bf(v1.y); o[6] = (short)f2bf(v1.z); o[7] = (short)f2bf(v1.w);
        *(s16x8*)(dstp + j * 8) = o;
      }
      const s16x8* bsrc = (const s16x8*)(WTqkv + (size_t)(n0 + arow) * 1024 + k0 + ahalf * 32);
      unsigned short* bdst = &Bs[arow][ahalf * 32];
#pragma unroll
      for (int j = 0; j < 4; ++j) *(s16x8*)(bdst + j * 8) = bsrc[j];
    }
    __syncthreads();
#pragma unroll
    for (int ks = 0; ks < 2; ++ks) {
      s16x8 af[4], bf[4];
#pragma unroll
      for (int i = 0; i < 4; ++i) af[i] = *(const s16x8*)&As[wm + i * 16 + lr][ks * 32 + lg * 8];
#pragma unroll
      for (int i = 0; i < 4; ++i) bf[i] = *(const s16x8*)&Bs[wn + i * 16 + lr][ks * 32 + lg * 8];
#pragma unroll
      for (int mi = 0; mi < 4; ++mi)
#pragma unroll
        for (int ni = 0; ni < 4; ++ni)
          acc[mi][ni] = __builtin_amdgcn_mfma_f32_16x16x32_bf16(af[mi], bf[ni], acc[mi][ni], 0, 0, 0);
    }
  }

#pragma unroll
  for (int ni = 0; ni < 4; ++ni) {
    int n = n0 + wn + ni * 16 + lr;
    int np = n & 1023;
    float bval = bias[np];
    int h = np >> 6, d = np & 63;
    int ia = d >> 1;
#pragma unroll
    for (int mi = 0; mi < 4; ++mi) {
#pragma unroll
      for (int r = 0; r < 4; ++r) {
        int m = m0 + wm + mi * 16 + lg * 4 + r;
        int s = m & 2047, b = m >> 11;
        float val = acc[mi][ni][r] + bval;
        size_t oidx = ((size_t)(b * 16 + h) * 2048 + s) * 64 + d;
        if (widx == 2) {
          vl[oidx] = f2bf(val);
        } else {
          float part = __shfl_xor(val, 1);
          float c = cosT[s * 32 + ia], sn = sinT[s * 32 + ia];
          float outv = (d & 1) ? (val * c + part * sn) : (val * c - part * sn);
          (widx == 0 ? ql : kl)[oidx] = f2bf(outv);
        }
      }
    }
  }
}

// ---------------- fused attention: scores out + online softmax + PV ----------------
__global__ __launch_bounds__(256) void k_attn(
    const unsigned short* __restrict__ ql, const unsigned short* __restrict__ kl,
    const unsigned short* __restrict__ vt, const float* __restrict__ prev,
    float* __restrict__ scores, unsigned short* __restrict__ attn_out) {
  __shared__ unsigned short Ks[128][72];
  __shared__ unsigned short Vs[64][136];
  __shared__ unsigned short Ps[4][16][136];
  const int bh = blockIdx.y;         // b*16+h
  const int q0 = blockIdx.x * 64;
  const int tid = threadIdx.x, lane = tid & 63, wave = tid >> 6;
  const int lr = lane & 15, lg = lane >> 4;
  const int qw = q0 + wave * 16;

  s16x8 qf[2];
#pragma unroll
  for (int ks = 0; ks < 2; ++ks)
    qf[ks] = *(const s16x8*)(ql + ((size_t)bh * 2048 + qw + lr) * 64 + ks * 32 + lg * 8);

  f32x4 o[4] = {};
  float m_run[4], l_run[4];
#pragma unroll
  for (int r = 0; r < 4; ++r) { m_run[r] = -1e30f; l_run[r] = 0.f; }

  const float scale = 0.125f;
  const float* prevB = prev + (size_t)bh * S_LEN * S_LEN;
  float* scoB = scores + (size_t)bh * S_LEN * S_LEN;

  const int sr = tid >> 1, shf = tid & 1;  // K staging
  const int dv = tid >> 2, q4 = tid & 3;   // V staging

  for (int kv0 = 0; kv0 < 2048; kv0 += 128) {
    __syncthreads();
    {
      const s16x8* ksrc = (const s16x8*)(kl + ((size_t)bh * 2048 + kv0 + sr) * 64 + shf * 32);
#pragma unroll
      for (int j = 0; j < 4; ++j) *(s16x8*)&Ks[sr][shf * 32 + j * 8] = ksrc[j];
      const s16x8* vsrc = (const s16x8*)(vt + (size_t)bh * DKH * S_LEN + (size_t)dv * S_LEN + kv0 + q4 * 32);
#pragma unroll
      for (int j = 0; j < 4; ++j) *(s16x8*)&Vs[dv][q4 * 32 + j * 8] = vsrc[j];
    }
    __syncthreads();

    f32x4 sc[8];
#pragma unroll
    for (int n = 0; n < 8; ++n) {
      f32x4 a = {};
#pragma unroll
      for (int ks = 0; ks < 2; ++ks) {
        s16x8 kf = *(const s16x8*)&Ks[n * 16 + lr][ks * 32 + lg * 8];
        a = __builtin_amdgcn_mfma_f32_16x16x32_bf16(qf[ks], kf, a, 0, 0, 0);
      }
      sc[n] = a;
    }

    float tmax[4] = {-1e30f, -1e30f, -1e30f, -1e30f};
#pragma unroll
    for (int n = 0; n < 8; ++n) {
      int col = kv0 + n * 16 + lr;
#pragma unroll
      for (int r = 0; r < 4; ++r) {
        int row = qw + lg * 4 + r;
        float v = sc[n][r] * scale + prevB[(size_t)row * S_LEN + col];
        scoB[(size_t)row * S_LEN + col] = v;
        sc[n][r] = v;
        tmax[r] = fmaxf(tmax[r], v);
      }
    }
#pragma unroll
    for (int mask = 1; mask < 16; mask <<= 1)
#pragma unroll
      for (int r = 0; r < 4; ++r) tmax[r] = fmaxf(tmax[r], __shfl_xor(tmax[r], mask));

    float al[4];
#pragma unroll
    for (int r = 0; r < 4; ++r) {
      float mn = fmaxf(m_run[r], tmax[r]);
      al[r] = __expf(m_run[r] - mn);
      m_run[r] = mn;
      l_run[r] *= al[r];
    }
#pragma unroll
    for (int df = 0; df < 4; ++df)
#pragma unroll
      for (int r = 0; r < 4; ++r) o[df][r] *= al[r];

#pragma unroll
    for (int n = 0; n < 8; ++n) {
#pragma unroll
      for (int r = 0; r < 4; ++r) {
        float p = __expf(sc[n][r] - m_run[r]);
        l_run[r] += p;
        Ps[wave][lg * 4 + r][n * 16 + lr] = f2bf(p);
      }
    }
    __syncthreads();  // ensure this wave's P writes visible to its own lanes' reads

#pragma unroll
    for (int df = 0; df < 4; ++df) {
#pragma unroll
      for (int ks = 0; ks < 4; ++ks) {
        s16x8 pa = *(const s16x8*)&Ps[wave][lr][ks * 32 + lg * 8];
        s16x8 vb = *(const s16x8*)&Vs[df * 16 + lr][ks * 32 + lg * 8];
        o[df] = __builtin_amdgcn_mfma_f32_16x16x32_bf16(pa, vb, o[df], 0, 0, 0);
      }
    }
  }

#pragma unroll
  for (int mask = 1; mask < 16; mask <<= 1)
#pragma unroll
    for (int r = 0; r < 4; ++r) l_run[r] += __shfl_xor(l_run[r], mask);
  float inv[4];
#pragma unroll
  for (int r = 0; r < 4; ++r) inv[r] = 1.0f / l_run[r];

  int b = bh >> 4, h = bh & 15;
#pragma unroll
  for (int df = 0; df < 4; ++df) {
    int d = df * 16 + lr;
#pragma unroll
    for (int r = 0; r < 4; ++r) {
      int row = qw + lg * 4 + r;
      attn_out[((size_t)(b * 2048 + row)) * 1024 + h * 64 + d] = f2bf(o[df][r] * inv[r]);
    }
  }
}

// ---------------- output projection GEMM ----------------
__global__ __launch_bounds__(256) void k_outproj(
    const unsigned short* __restrict__ A, const unsigned short* __restrict__ WoT,
    const float* __restrict__ bo, float* __restrict__ out) {
  __shared__ unsigned short As[128][72];
  __shared__ unsigned short Bs[128][72];
  const int m0 = blockIdx.y * 128, n0 = blockIdx.x * 128;
  const int tid = threadIdx.x, lane = tid & 63, wave = tid >> 6;
  const int wm = (wave >> 1) * 64, wn = (wave & 1) * 64;
  const int lr = lane & 15, lg = lane >> 4;
  f32x4 acc[4][4] = {};
  const int r = tid >> 1, hfl = tid & 1;
  for (int k0 = 0; k0 < 1024; k0 += 64) {
    __syncthreads();
    const s16x8* asrc = (const s16x8*)(A + (size_t)(m0 + r) * 1024 + k0 + hfl * 32);
    const s16x8* bsrc = (const s16x8*)(WoT + (size_t)(n0 + r) * 1024 + k0 + hfl * 32);
#pragma unroll
    for (int j = 0; j < 4; ++j) {
      *(s16x8*)&As[r][hfl * 32 + j * 8] = asrc[j];
      *(s16x8*)&Bs[r][hfl * 32 + j * 8] = bsrc[j];
    }
    __syncthreads();
#pragma unroll
    for (int ks = 0; ks < 2; ++ks) {
      s16x8 af[4], bf[4];
#pragma unroll
      for (int i = 0; i < 4; ++i) af[i] = *(const s16x8*)&As[wm + i * 16 + lr][ks * 32 + lg * 8];
#pragma unroll
      for (int i = 0; i < 4; ++i) bf[i] = *(const s16x8*)&Bs[wn + i * 16 + lr][ks * 32 + lg * 8];
#pragma unroll
      for (int mi = 0; mi < 4; ++mi)
#pragma unroll
        for (int ni = 0; ni < 4; ++ni)
          acc[mi][ni] = __builtin_amdgcn_mfma_f32_16x16x32_bf16(af[mi], bf[ni], acc[mi][ni], 0, 0, 0);
    }
  }
#pragma unroll
  for (int ni = 0; ni < 4; ++ni) {
    int n = n0 + wn + ni * 16 + lr;
    float bv = bo[n];
#pragma unroll
    for (int mi = 0; mi < 4; ++mi)
#pragma unroll
      for (int rr = 0; rr < 4; ++rr) {
        int m = m0 + wm + mi * 16 + lg * 4 + rr;
        out[(size_t)m * 1024 + n] = acc[mi][ni][rr] + bv;
      }
  }
}

extern "C" void kernel_launch(void* const* d_in, const int* in_sizes, int n_in,
                              void* d_out, int out_size, void* d_ws, size_t ws_size,
                              hipStream_t stream) {
  const float* Q = (const float*)d_in[0];
  const float* prev = (const float*)d_in[1];
  const float* Wq = (const float*)d_in[2];
  const float* bq = (const float*)d_in[3];
  const float* Wk = (const float*)d_in[4];
  const float* bk = (const float*)d_in[5];
  const float* Wv = (const float*)d_in[6];
  const float* bv = (const float*)d_in[7];
  const float* Wo = (const float*)d_in[8];
  const float* bo = (const float*)d_in[9];

  float* out = (float*)d_out;
  float* scores = out + (size_t)4194304;  // 2*2048*1024 elements of "out", then scores

  char* ws = (char*)d_ws;
  float* cosT = (float*)ws;
  float* sinT = cosT + 65536;
  unsigned short* WTqkv = (unsigned short*)(ws + 524288);  // [3072][1024]
  unsigned short* WoT = WTqkv + 3145728;                   // [1024][1024]
  unsigned short* ql = WoT + 1048576;                      // [32][2048][64]
  unsigned short* kl = ql + 4194304;
  unsigned short* vl = kl + 4194304;
  unsigned short* vt = vl + 4194304;                       // [32][64][2048]
  unsigned short* attn_out = vt + 4194304;                 // [4096][1024]

  k_rope_table<<<256, 256, 0, stream>>>(cosT, sinT);
  k_wtrans<<<dim3(32, 32), 256, 0, stream>>>(Wq, WTqkv);
  k_wtrans<<<dim3(32, 32), 256, 0, stream>>>(Wk, WTqkv + 1048576);
  k_wtrans<<<dim3(32, 32), 256, 0, stream>>>(Wv, WTqkv + 2097152);
  k_wtrans<<<dim3(32, 32), 256, 0, stream>>>(Wo, WoT);
  k_qkv<<<dim3(24, 32), 256, 0, stream>>>(Q, WTqkv, bq, bk, bv, cosT, sinT, ql, kl, vl);
  k_vtrans<<<dim3(32, 32), 256, 0, stream>>>(vl, vt);
  k_attn<<<dim3(32, 32), 256, 0, stream>>>(ql, kl, vt, prev, scores, attn_out);
  k_outproj<<<dim3(8, 32), 256, 0, stream>>>(attn_out, WoT, bo, out);
}